// Round 3
// baseline (455.622 us; speedup 1.0000x reference)
//
#include <hip/hip_runtime.h>
#include <hip/hip_bf16.h>
#include <stdint.h>

typedef float floatx4 __attribute__((ext_vector_type(4)));
typedef __bf16 bfx8 __attribute__((ext_vector_type(8)));

#define ATT_SCALE 0.08838834764831845f

__device__ __forceinline__ uint16_t f2bf(float f) {
  uint32_t u = __float_as_uint(f);
  return (uint16_t)((u + 0x7fffu + ((u >> 16) & 1u)) >> 16);
}
__device__ __forceinline__ float bf2f(uint32_t bits16) {
  return __uint_as_float(bits16 << 16);
}

typedef __attribute__((address_space(3))) uint32_t lds_u32;
typedef const __attribute__((address_space(1))) uint32_t glob_u32;

// async global->LDS, 16B per lane. LDS dest is wave-uniform base + lane*16.
__device__ __forceinline__ void async_copy16(void* lds, const void* g) {
  uint32_t loff = (uint32_t)(uintptr_t)lds;
  loff = (uint32_t)__builtin_amdgcn_readfirstlane((int)loff);
  lds_u32* lp = reinterpret_cast<lds_u32*>(loff);
  glob_u32* gp = reinterpret_cast<glob_u32*>((uintptr_t)g);
  __builtin_amdgcn_global_load_lds(gp, lp, 16, 0, 0);
}

// ---------------------------------------------------------------------------
// fp32 -> bf16 convert, 4 elems/thread
__global__ void cvt_kernel(const float* __restrict__ in, uint16_t* __restrict__ out, int n) {
  int i = (blockIdx.x * 256 + threadIdx.x) << 2;
  if (i >= n) return;
  const float4 v = *(const float4*)(in + i);
  uint32_t lo = (uint32_t)f2bf(v.x) | ((uint32_t)f2bf(v.y) << 16);
  uint32_t hi = (uint32_t)f2bf(v.z) | ((uint32_t)f2bf(v.w) << 16);
  *(uint2*)(out + i) = make_uint2(lo, hi);
}

// ---------------------------------------------------------------------------
// in-place RoPE on bf16 buffer laid out (token, ncols); one thread per pair.
// post = extra scalar folded into the rotation (ATT_SCALE for Q, 1 for K).
__global__ void rope_kernel(uint32_t* __restrict__ buf, const float* __restrict__ freq,
                            int shift, int total, float post) {
  int idx = blockIdx.x * 256 + threadIdx.x;
  if (idx >= total) return;
  int row = idx >> shift;
  int cp  = idx & ((1 << shift) - 1);
  int s = row & 2047;
  int f = cp & 63;
  float fr = freq[(s << 6) + f];
  float sn, c;
  sincosf(fr, &sn, &c);
  uint32_t u = buf[idx];
  float xr = bf2f(u & 0xffffu);
  float xi = bf2f(u >> 16);
  float orr = (xr * c - xi * sn) * post;
  float oi  = (xr * sn + xi * c) * post;
  buf[idx] = (uint32_t)f2bf(orr) | ((uint32_t)f2bf(oi) << 16);
}

// ---------------------------------------------------------------------------
// 8-wave counted-vmcnt GEMM: C[M][N] = A[M x K=2048] * W[N x K]^T (+bias).
// BM x 256 tile, BK=64, 2 sub-phases per K-tile, raw s_barrier (no vmcnt(0)
// drain in the main loop), both-sides XOR swizzle via pre-swizzled
// global_load_lds source. Wave grid WGM x (8/WGM); per-wave 128 x (256*WGM/8).
// MODE 0: QKV fused epilogue (Q/K bf16 token-major, V bf16 transposed d-major)
// MODE 1: fp32 out + bias
template <int BM, int WGM, int MODE>
__global__ __launch_bounds__(512, 2) void gemm256(
    const uint16_t* __restrict__ A,
    const uint16_t* __restrict__ Wq, const uint16_t* __restrict__ Wk,
    const uint16_t* __restrict__ Wv,
    const float* __restrict__ bq, const float* __restrict__ bk,
    const float* __restrict__ bv,
    uint16_t* __restrict__ Qo, uint16_t* __restrict__ Ko,
    uint16_t* __restrict__ Vt, float* __restrict__ Fo) {
  constexpr int BN = 256;
  constexpr int NT = 32;                 // K = 2048, BK = 64
  constexpr int WGN = 8 / WGM;
  constexpr int WN = BN / WGN;           // 64 (QKV) or 32 (out-proj)
  constexpr int NR = WN / 16;            // 4 or 2
  constexpr int AI = BM / 64;            // A stage instrs per wave (4 or 2)
  constexpr int NL = AI + 4;             // loads per K-tile per wave (8 or 6)

  const int tid  = threadIdx.x;
  const int w    = tid >> 6;
  const int lane = tid & 63;
  const int l15  = lane & 15;
  const int l4   = lane >> 4;
  const int bm = blockIdx.x * BM;
  const int n0 = blockIdx.y * BN;

  const uint16_t* Wp;
  int wrow;
  if constexpr (MODE == 0) {
    if (n0 < 2048)      { Wp = Wq; wrow = n0; }
    else if (n0 < 2560) { Wp = Wk; wrow = n0 - 2048; }
    else                { Wp = Wv; wrow = n0 - 2560; }
  } else {
    Wp = Wq; wrow = n0;
  }

  __shared__ uint16_t As[2][BM * 64];
  __shared__ uint16_t Bs[2][BN * 64];

  const int wr = w / WGN;                // 0..WGM-1
  const int wc = w % WGN;                // 0..WGN-1

  floatx4 acc[8][NR] = {};

  const int srow = lane >> 3;            // row within 8-row copy
  const int sx   = lane & 7;

  auto stageA = [&](int buf, int t) {
#pragma unroll
    for (int i = 0; i < AI; ++i) {
      const int base_r = w * (BM / 8) + 8 * i;
      const int r = base_r + srow;
      const char* src = (const char*)A + ((size_t)(bm + r) * 2048 + t * 64) * 2 + ((sx ^ (r & 7)) << 4);
      async_copy16((char*)(As[buf]) + base_r * 128, src);
    }
  };
  auto stageB = [&](int buf, int t) {
#pragma unroll
    for (int i = 0; i < 4; ++i) {
      const int base_r = w * 32 + 8 * i;
      const int r = base_r + srow;
      const char* src = (const char*)Wp + ((size_t)(wrow + r) * 2048 + t * 64) * 2 + ((sx ^ (r & 7)) << 4);
      async_copy16((char*)(Bs[buf]) + base_r * 128, src);
    }
  };

  // prologue: K0 -> buf0, K1 -> buf1; wait for K0 only (K1 stays in flight)
  stageA(0, 0); stageB(0, 0);
  stageA(1, 1); stageB(1, 1);
  if constexpr (NL == 8) asm volatile("s_waitcnt vmcnt(8)" ::: "memory");
  else                   asm volatile("s_waitcnt vmcnt(6)" ::: "memory");
  __builtin_amdgcn_s_barrier();

  for (int t = 0; t < NT; ++t) {
    const int cur = t & 1;
    const char* AsB = (const char*)(As[cur]);
    const char* BsB = (const char*)(Bs[cur]);

    // sub-phase kk=0: frags + MFMA
    bfx8 a0[8], b0[NR];
#pragma unroll
    for (int n = 0; n < NR; ++n) {
      const int r = wc * WN + n * 16 + l15;
      b0[n] = *(const bfx8*)(BsB + r * 128 + ((l4 << 4) ^ ((r & 7) << 4)));
    }
#pragma unroll
    for (int m = 0; m < 8; ++m) {
      const int r = wr * 128 + m * 16 + l15;
      a0[m] = *(const bfx8*)(AsB + r * 128 + ((l4 << 4) ^ ((r & 7) << 4)));
    }
    __builtin_amdgcn_s_setprio(1);
#pragma unroll
    for (int m = 0; m < 8; ++m)
#pragma unroll
      for (int n = 0; n < NR; ++n)
        acc[m][n] = __builtin_amdgcn_mfma_f32_16x16x32_bf16(a0[m], b0[n], acc[m][n], 0, 0, 0);
    __builtin_amdgcn_s_setprio(0);

    // sub-phase kk=1: frags, then barrier #1 (all reads of buf[cur] complete)
    bfx8 a1[8], b1[NR];
#pragma unroll
    for (int n = 0; n < NR; ++n) {
      const int r = wc * WN + n * 16 + l15;
      b1[n] = *(const bfx8*)(BsB + r * 128 + ((64 + (l4 << 4)) ^ ((r & 7) << 4)));
    }
#pragma unroll
    for (int m = 0; m < 8; ++m) {
      const int r = wr * 128 + m * 16 + l15;
      a1[m] = *(const bfx8*)(AsB + r * 128 + ((64 + (l4 << 4)) ^ ((r & 7) << 4)));
    }
    asm volatile("s_waitcnt lgkmcnt(0)" ::: "memory");
    __builtin_amdgcn_sched_barrier(0);
    __builtin_amdgcn_s_barrier();                    // #1
    if (t + 2 < NT) { stageA(cur, t + 2); stageB(cur, t + 2); }
    __builtin_amdgcn_sched_barrier(0);
    __builtin_amdgcn_s_setprio(1);
#pragma unroll
    for (int m = 0; m < 8; ++m)
#pragma unroll
      for (int n = 0; n < NR; ++n)
        acc[m][n] = __builtin_amdgcn_mfma_f32_16x16x32_bf16(a1[m], b1[n], acc[m][n], 0, 0, 0);
    __builtin_amdgcn_s_setprio(0);
    // counted wait: K(t+1) landed, K(t+2) stays in flight. Drain at the tail.
    if (t < NT - 2) {
      if constexpr (NL == 8) asm volatile("s_waitcnt vmcnt(8)" ::: "memory");
      else                   asm volatile("s_waitcnt vmcnt(6)" ::: "memory");
    } else if (t == NT - 2) {
      asm volatile("s_waitcnt vmcnt(0)" ::: "memory");
    }
    __builtin_amdgcn_s_barrier();                    // #2
  }

  // epilogue: D row = (lane>>4)*4 + reg, col = lane&15
  const int rb = bm + wr * 128 + (l4 << 2);
  const int cl = wc * WN + l15;
#pragma unroll
  for (int n = 0; n < NR; ++n) {
    const int c = n0 + cl + (n << 4);
#pragma unroll
    for (int m = 0; m < 8; ++m) {
      const int r0 = rb + (m << 4);
      if constexpr (MODE == 1) {
        const float bias = bq[c];
#pragma unroll
        for (int j = 0; j < 4; ++j)
          Fo[(size_t)(r0 + j) * 2048 + c] = acc[m][n][j] + bias;
      } else {
        if (n0 < 2048) {
          const float bias = bq[c];
#pragma unroll
          for (int j = 0; j < 4; ++j)
            Qo[(size_t)(r0 + j) * 2048 + c] = f2bf(acc[m][n][j] + bias);
        } else if (n0 < 2560) {
          const int ck = c - 2048;
          const float bias = bk[ck];
#pragma unroll
          for (int j = 0; j < 4; ++j)
            Ko[(size_t)(r0 + j) * 512 + ck] = f2bf(acc[m][n][j] + bias);
        } else {
          const int cv = c - 2560;
          const float bias = bv[cv];
          const int b = r0 >> 11, s = r0 & 2047;
          const int kv = cv >> 7, dh = cv & 127;
          uint32_t lo = (uint32_t)f2bf(acc[m][n][0] + bias) | ((uint32_t)f2bf(acc[m][n][1] + bias) << 16);
          uint32_t hi = (uint32_t)f2bf(acc[m][n][2] + bias) | ((uint32_t)f2bf(acc[m][n][3] + bias) << 16);
          *(uint2*)(Vt + (size_t)(((b << 2) + kv) * 128 + dh) * 2048 + s) = make_uint2(lo, hi);
        }
      }
    }
  }
}

// ---------------------------------------------------------------------------
// Causal GQA flash attention, balanced pairs + double-buffered K/V staging.
// Q is pre-scaled by ATT_SCALE (folded into RoPE).
__global__ __launch_bounds__(256) void attn_kernel(
    const uint16_t* __restrict__ Q, const uint16_t* __restrict__ Kb,
    const uint16_t* __restrict__ Vt, uint16_t* __restrict__ O) {
  const int px  = blockIdx.x;          // pair index 0..15
  const int h   = blockIdx.y;
  const int b   = blockIdx.z;
  const int kvh = h >> 2;
  const int tid  = threadIdx.x;
  const int w    = tid >> 6;
  const int lane = tid & 63;
  const int l15 = lane & 15;
  const int l4  = lane >> 4;

  __shared__ uint16_t Ks[2][64 * 128];
  __shared__ uint16_t Vs[2][128 * 64];
  __shared__ uint16_t Ps[4][16 * 64];
  char* PsB = (char*)(Ps[w]);

  const int krow_off = l4;
  const int kscb = l15 << 4;
  const int vrow_off = lane >> 3;
  const int vscb = (lane & 7) << 4;

  auto stageK = [&](int buf, int t) {
    const int kb = t << 6;
#pragma unroll
    for (int i = 0; i < 4; ++i) {
      const int base_r = 16 * w + 4 * i;
      const int r = base_r + krow_off;
      const int scb = kscb ^ ((r & 7) << 4);
      const char* src = (const char*)Kb + ((size_t)(b * 2048 + kb + r) * 512 + kvh * 128) * 2 + scb;
      async_copy16((char*)(Ks[buf]) + base_r * 256, src);
    }
  };
  auto stageV = [&](int buf, int t) {
    const int kb = t << 6;
#pragma unroll
    for (int i = 0; i < 4; ++i) {
      const int base_r = 32 * w + 8 * i;
      const int r = base_r + vrow_off;
      const int scb = vscb ^ ((r & 7) << 4);
      const char* src = (const char*)Vt + ((size_t)(((b << 2) + kvh) * 128 + r) * 2048 + kb) * 2 + scb;
      async_copy16((char*)(Vs[buf]) + base_r * 128, src);
    }
  };

  for (int half = 0; half < 2; ++half) {
    const int qt = half ? (31 - px) : px;
    const int qbase = qt << 6;

    bfx8 qf[4];
    {
      const size_t qrow = (size_t)(b * 2048 + qbase + (w << 4) + l15);
      const char* qp = (const char*)(Q + qrow * 2048 + h * 128 + l4 * 8);
#pragma unroll
      for (int kk = 0; kk < 4; ++kk) qf[kk] = *(const bfx8*)(qp + kk * 64);
    }

    floatx4 oacc[8] = {};
    float mrun[4], lrun[4];
#pragma unroll
    for (int j = 0; j < 4; ++j) { mrun[j] = -1e30f; lrun[j] = 0.0f; }

    stageK(0, 0);
    stageV(0, 0);
    __syncthreads();

    for (int t = 0; t <= qt; ++t) {
      const int cur = t & 1;
      if (t < qt) { stageK(cur ^ 1, t + 1); stageV(cur ^ 1, t + 1); }
      char* KsB = (char*)(Ks[cur]);
      char* VsB = (char*)(Vs[cur]);
      const int kb = t << 6;

      // S = Q K^T (Q pre-scaled)
      floatx4 sc[4] = {};
      __builtin_amdgcn_s_setprio(1);
#pragma unroll
      for (int kk = 0; kk < 4; ++kk) {
        const int cb = (kk << 6) + (l4 << 4);
#pragma unroll
        for (int n = 0; n < 4; ++n) {
          const int r = (n << 4) + l15;
          bfx8 kf = *(const bfx8*)(KsB + r * 256 + (cb ^ ((r & 7) << 4)));
          sc[n] = __builtin_amdgcn_mfma_f32_16x16x32_bf16(qf[kk], kf, sc[n], 0, 0, 0);
        }
      }
      __builtin_amdgcn_s_setprio(0);

      float p[4][4];
      const bool diag = (t == qt);
#pragma unroll
      for (int n = 0; n < 4; ++n) {
#pragma unroll
        for (int j = 0; j < 4; ++j) {
          float v = sc[n][j];
          if (diag) {
            const int col = kb + (n << 4) + l15;
            const int row = qbase + (w << 4) + (l4 << 2) + j;
            if (col > row) v = -1e30f;
          }
          p[n][j] = v;
        }
      }

      // online softmax; rescale skipped exactly when no lane saw a new max
#pragma unroll
      for (int j = 0; j < 4; ++j) {
        float pm = fmaxf(fmaxf(p[0][j], p[1][j]), fmaxf(p[2][j], p[3][j]));
#pragma unroll
        for (int off = 8; off > 0; off >>= 1) pm = fmaxf(pm, __shfl_xor(pm, off, 64));
        if (__any(pm > mrun[j])) {
          const float mnew = fmaxf(mrun[j], pm);
          const float sf = __expf(mrun[j] - mnew);
          mrun[j] = mnew;
          float rs = 0.f;
#pragma unroll
          for (int n = 0; n < 4; ++n) {
            p[n][j] = __expf(p[n][j] - mnew);
            rs += p[n][j];
          }
          lrun[j] = lrun[j] * sf + rs;
#pragma unroll
          for (int d = 0; d < 8; ++d) oacc[d][j] *= sf;
        } else {
          float rs = 0.f;
#pragma unroll
          for (int n = 0; n < 4; ++n) {
            p[n][j] = __expf(p[n][j] - mrun[j]);
            rs += p[n][j];
          }
          lrun[j] += rs;
        }
      }

      // P -> per-wave LDS (wave-private, no barrier)
#pragma unroll
      for (int n = 0; n < 4; ++n) {
        const int cbw = (n << 5) + (l15 << 1);
#pragma unroll
        for (int j = 0; j < 4; ++j) {
          const int r = (l4 << 2) + j;
          *(uint16_t*)(PsB + r * 128 + (cbw ^ ((r & 7) << 4))) = f2bf(p[n][j]);
        }
      }

      // O += P V
      __builtin_amdgcn_s_setprio(1);
#pragma unroll
      for (int kk = 0; kk < 2; ++kk) {
        const int cb = (kk << 6) + (l4 << 4);
        bfx8 pf = *(const bfx8*)(PsB + l15 * 128 + (cb ^ ((l15 & 7) << 4)));
#pragma unroll
        for (int d = 0; d < 8; ++d) {
          const int r = (d << 4) + l15;
          bfx8 vf = *(const bfx8*)(VsB + r * 128 + (cb ^ ((r & 7) << 4)));
          oacc[d] = __builtin_amdgcn_mfma_f32_16x16x32_bf16(pf, vf, oacc[d], 0, 0, 0);
        }
      }
      __builtin_amdgcn_s_setprio(0);

      __syncthreads();
    }

    // epilogue: reduce lrun across 16 lanes, normalize, store bf16
#pragma unroll
    for (int j = 0; j < 4; ++j) {
      float l = lrun[j];
#pragma unroll
      for (int off = 8; off > 0; off >>= 1) l += __shfl_xor(l, off, 64);
      const float inv = 1.0f / l;
      const size_t row = (size_t)(b * 2048 + qbase + (w << 4) + (l4 << 2) + j);
#pragma unroll
      for (int d = 0; d < 8; ++d) {
        const int c = h * 128 + (d << 4) + l15;
        O[row * 2048 + c] = f2bf(oacc[d][j] * inv);
      }
    }
  }
}

// ---------------------------------------------------------------------------
extern "C" void kernel_launch(void* const* d_in, const int* in_sizes, int n_in,
                              void* d_out, int out_size, void* d_ws, size_t ws_size,
                              hipStream_t stream) {
  (void)in_sizes; (void)n_in; (void)out_size; (void)ws_size;
  const float* x         = (const float*)d_in[0];
  const float* rope_freq = (const float*)d_in[1];
  const float* wq_w = (const float*)d_in[3];
  const float* wq_b = (const float*)d_in[4];
  const float* wk_w = (const float*)d_in[5];
  const float* wk_b = (const float*)d_in[6];
  const float* wv_w = (const float*)d_in[7];
  const float* wv_b = (const float*)d_in[8];
  const float* wo_w = (const float*)d_in[9];
  const float* wo_b = (const float*)d_in[10];
  float* out = (float*)d_out;

  char* ws = (char*)d_ws;
  uint16_t* xbf = (uint16_t*)(ws + 0);          // 16 MB : x bf16 (4096,2048)
  uint16_t* wqb = (uint16_t*)(ws + 16777216);   //  8 MB
  uint16_t* wkb = (uint16_t*)(ws + 25165824);   //  2 MB
  uint16_t* wvb = (uint16_t*)(ws + 27262976);   //  2 MB
  uint16_t* wob = (uint16_t*)(ws + 29360128);   //  8 MB
  uint16_t* qbf = (uint16_t*)(ws + 37748736);   // 16 MB : Q (token,2048)
  uint16_t* kbf = (uint16_t*)(ws + 54525952);   //  4 MB : K (token,512)
  uint16_t* vtb = (uint16_t*)(ws + 58720256);   //  4 MB : V^T (b,kv,128,2048)
  uint16_t* att = (uint16_t*)(ws + 62914560);   // 16 MB : attn out (token,2048)

  cvt_kernel<<<8192, 256, 0, stream>>>(x, xbf, 8388608);
  cvt_kernel<<<4096, 256, 0, stream>>>(wq_w, wqb, 4194304);
  cvt_kernel<<<1024, 256, 0, stream>>>(wk_w, wkb, 1048576);
  cvt_kernel<<<1024, 256, 0, stream>>>(wv_w, wvb, 1048576);
  cvt_kernel<<<4096, 256, 0, stream>>>(wo_w, wob, 4194304);

  gemm256<256, 2, 0><<<dim3(16, 12), 512, 0, stream>>>(
      xbf, wqb, wkb, wvb, wq_b, wk_b, wv_b, qbf, kbf, vtb, nullptr);

  rope_kernel<<<16384, 256, 0, stream>>>((uint32_t*)qbf, rope_freq, 10, 4194304, ATT_SCALE);
  rope_kernel<<<4096, 256, 0, stream>>>((uint32_t*)kbf, rope_freq, 8, 1048576, 1.0f);

  attn_kernel<<<dim3(16, 16, 2), 256, 0, stream>>>(qbf, kbf, vtb, att);

  gemm256<128, 1, 1><<<dim3(32, 8), 512, 0, stream>>>(
      att, wob, nullptr, nullptr, wo_b, nullptr, nullptr,
      nullptr, nullptr, nullptr, out);
}

// Round 6
// 354.569 us; speedup vs baseline: 1.2850x; 1.2850x over previous
//
#include <hip/hip_runtime.h>
#include <hip/hip_bf16.h>
#include <stdint.h>

typedef float floatx4 __attribute__((ext_vector_type(4)));
typedef __bf16 bfx8 __attribute__((ext_vector_type(8)));

#define ATT_SCALE 0.08838834764831845f

__device__ __forceinline__ uint16_t f2bf(float f) {
  uint32_t u = __float_as_uint(f);
  return (uint16_t)((u + 0x7fffu + ((u >> 16) & 1u)) >> 16);
}
__device__ __forceinline__ float bf2f(uint32_t bits16) {
  return __uint_as_float(bits16 << 16);
}

typedef __attribute__((address_space(3))) uint32_t lds_u32;
typedef const __attribute__((address_space(1))) uint32_t glob_u32;

// async global->LDS, 16B per lane. LDS dest is wave-uniform base + lane*16.
__device__ __forceinline__ void async_copy16(void* lds, const void* g) {
  uint32_t loff = (uint32_t)(uintptr_t)lds;
  loff = (uint32_t)__builtin_amdgcn_readfirstlane((int)loff);
  lds_u32* lp = reinterpret_cast<lds_u32*>(loff);
  glob_u32* gp = reinterpret_cast<glob_u32*>((uintptr_t)g);
  __builtin_amdgcn_global_load_lds(gp, lp, 16, 0, 0);
}

// ---------------------------------------------------------------------------
// fp32 -> bf16 convert, 4 elems/thread
__global__ void cvt_kernel(const float* __restrict__ in, uint16_t* __restrict__ out, int n) {
  int i = (blockIdx.x * 256 + threadIdx.x) << 2;
  if (i >= n) return;
  const float4 v = *(const float4*)(in + i);
  uint32_t lo = (uint32_t)f2bf(v.x) | ((uint32_t)f2bf(v.y) << 16);
  uint32_t hi = (uint32_t)f2bf(v.z) | ((uint32_t)f2bf(v.w) << 16);
  *(uint2*)(out + i) = make_uint2(lo, hi);
}

// ---------------------------------------------------------------------------
// in-place RoPE on bf16 buffer laid out (token, ncols); one thread per pair.
// post = extra scalar folded into the rotation (ATT_SCALE for Q, 1 for K).
__global__ void rope_kernel(uint32_t* __restrict__ buf, const float* __restrict__ freq,
                            int shift, int total, float post) {
  int idx = blockIdx.x * 256 + threadIdx.x;
  if (idx >= total) return;
  int row = idx >> shift;
  int cp  = idx & ((1 << shift) - 1);
  int s = row & 2047;
  int f = cp & 63;
  float fr = freq[(s << 6) + f];
  float sn, c;
  sincosf(fr, &sn, &c);
  uint32_t u = buf[idx];
  float xr = bf2f(u & 0xffffu);
  float xi = bf2f(u >> 16);
  float orr = (xr * c - xi * sn) * post;
  float oi  = (xr * sn + xi * c) * post;
  buf[idx] = (uint32_t)f2bf(orr) | ((uint32_t)f2bf(oi) << 16);
}

// ---------------------------------------------------------------------------
// 8-wave counted-vmcnt GEMM: C[M][N] = A[M x K=2048] * W[N x K]^T (+bias).
// BM x 256 tile, BK=64, 2 sub-phases per K-tile, raw s_barrier (no vmcnt(0)
// drain in the main loop), both-sides XOR swizzle via pre-swizzled
// global_load_lds source. Wave grid WGM x (8/WGM); per-wave 128 x (256*WGM/8).
// MODE 0: QKV fused epilogue (Q/K bf16 token-major, V bf16 transposed d-major)
// MODE 1: fp32 out + bias
template <int BM, int WGM, int MODE>
__global__ __launch_bounds__(512, 2) void gemm256(
    const uint16_t* __restrict__ A,
    const uint16_t* __restrict__ Wq, const uint16_t* __restrict__ Wk,
    const uint16_t* __restrict__ Wv,
    const float* __restrict__ bq, const float* __restrict__ bk,
    const float* __restrict__ bv,
    uint16_t* __restrict__ Qo, uint16_t* __restrict__ Ko,
    uint16_t* __restrict__ Vt, float* __restrict__ Fo) {
  constexpr int BN = 256;
  constexpr int NT = 32;                 // K = 2048, BK = 64
  constexpr int WGN = 8 / WGM;
  constexpr int WN = BN / WGN;           // 64 (QKV) or 32 (out-proj)
  constexpr int NR = WN / 16;            // 4 or 2
  constexpr int AI = BM / 64;            // A stage instrs per wave (4 or 2)
  constexpr int NL = AI + 4;             // loads per K-tile per wave (8 or 6)

  const int tid  = threadIdx.x;
  const int w    = tid >> 6;
  const int lane = tid & 63;
  const int l15  = lane & 15;
  const int l4   = lane >> 4;
  const int bm = blockIdx.x * BM;
  const int n0 = blockIdx.y * BN;

  const uint16_t* Wp;
  int wrow;
  if constexpr (MODE == 0) {
    if (n0 < 2048)      { Wp = Wq; wrow = n0; }
    else if (n0 < 2560) { Wp = Wk; wrow = n0 - 2048; }
    else                { Wp = Wv; wrow = n0 - 2560; }
  } else {
    Wp = Wq; wrow = n0;
  }

  __shared__ uint16_t As[2][BM * 64];
  __shared__ uint16_t Bs[2][BN * 64];

  const int wr = w / WGN;                // 0..WGM-1
  const int wc = w % WGN;                // 0..WGN-1

  floatx4 acc[8][NR] = {};

  const int srow = lane >> 3;            // row within 8-row copy
  const int sx   = lane & 7;

  auto stageA = [&](int buf, int t) {
#pragma unroll
    for (int i = 0; i < AI; ++i) {
      const int base_r = w * (BM / 8) + 8 * i;
      const int r = base_r + srow;
      const char* src = (const char*)A + ((size_t)(bm + r) * 2048 + t * 64) * 2 + ((sx ^ (r & 7)) << 4);
      async_copy16((char*)(As[buf]) + base_r * 128, src);
    }
  };
  auto stageB = [&](int buf, int t) {
#pragma unroll
    for (int i = 0; i < 4; ++i) {
      const int base_r = w * 32 + 8 * i;
      const int r = base_r + srow;
      const char* src = (const char*)Wp + ((size_t)(wrow + r) * 2048 + t * 64) * 2 + ((sx ^ (r & 7)) << 4);
      async_copy16((char*)(Bs[buf]) + base_r * 128, src);
    }
  };

  // prologue: K0 -> buf0, K1 -> buf1; wait for K0 only (K1 stays in flight)
  stageA(0, 0); stageB(0, 0);
  stageA(1, 1); stageB(1, 1);
  if constexpr (NL == 8) asm volatile("s_waitcnt vmcnt(8)" ::: "memory");
  else                   asm volatile("s_waitcnt vmcnt(6)" ::: "memory");
  __builtin_amdgcn_s_barrier();

  for (int t = 0; t < NT; ++t) {
    const int cur = t & 1;
    const char* AsB = (const char*)(As[cur]);
    const char* BsB = (const char*)(Bs[cur]);

    // sub-phase kk=0: frags + MFMA
    bfx8 a0[8], b0[NR];
#pragma unroll
    for (int n = 0; n < NR; ++n) {
      const int r = wc * WN + n * 16 + l15;
      b0[n] = *(const bfx8*)(BsB + r * 128 + ((l4 << 4) ^ ((r & 7) << 4)));
    }
#pragma unroll
    for (int m = 0; m < 8; ++m) {
      const int r = wr * 128 + m * 16 + l15;
      a0[m] = *(const bfx8*)(AsB + r * 128 + ((l4 << 4) ^ ((r & 7) << 4)));
    }
    __builtin_amdgcn_s_setprio(1);
#pragma unroll
    for (int m = 0; m < 8; ++m)
#pragma unroll
      for (int n = 0; n < NR; ++n)
        acc[m][n] = __builtin_amdgcn_mfma_f32_16x16x32_bf16(a0[m], b0[n], acc[m][n], 0, 0, 0);
    __builtin_amdgcn_s_setprio(0);

    // sub-phase kk=1: frags, then barrier #1 (all reads of buf[cur] complete)
    bfx8 a1[8], b1[NR];
#pragma unroll
    for (int n = 0; n < NR; ++n) {
      const int r = wc * WN + n * 16 + l15;
      b1[n] = *(const bfx8*)(BsB + r * 128 + ((64 + (l4 << 4)) ^ ((r & 7) << 4)));
    }
#pragma unroll
    for (int m = 0; m < 8; ++m) {
      const int r = wr * 128 + m * 16 + l15;
      a1[m] = *(const bfx8*)(AsB + r * 128 + ((64 + (l4 << 4)) ^ ((r & 7) << 4)));
    }
    asm volatile("s_waitcnt lgkmcnt(0)" ::: "memory");
    __builtin_amdgcn_sched_barrier(0);
    __builtin_amdgcn_s_barrier();                    // #1
    if (t + 2 < NT) { stageA(cur, t + 2); stageB(cur, t + 2); }
    __builtin_amdgcn_sched_barrier(0);
    __builtin_amdgcn_s_setprio(1);
#pragma unroll
    for (int m = 0; m < 8; ++m)
#pragma unroll
      for (int n = 0; n < NR; ++n)
        acc[m][n] = __builtin_amdgcn_mfma_f32_16x16x32_bf16(a1[m], b1[n], acc[m][n], 0, 0, 0);
    __builtin_amdgcn_s_setprio(0);
    // counted wait: K(t+1) landed, K(t+2) stays in flight. Drain at the tail.
    if (t < NT - 2) {
      if constexpr (NL == 8) asm volatile("s_waitcnt vmcnt(8)" ::: "memory");
      else                   asm volatile("s_waitcnt vmcnt(6)" ::: "memory");
    } else if (t == NT - 2) {
      asm volatile("s_waitcnt vmcnt(0)" ::: "memory");
    }
    __builtin_amdgcn_s_barrier();                    // #2
  }

  // epilogue: D row = (lane>>4)*4 + reg, col = lane&15
  const int rb = bm + wr * 128 + (l4 << 2);
  const int cl = wc * WN + l15;
#pragma unroll
  for (int n = 0; n < NR; ++n) {
    const int c = n0 + cl + (n << 4);
#pragma unroll
    for (int m = 0; m < 8; ++m) {
      const int r0 = rb + (m << 4);
      if constexpr (MODE == 1) {
        const float bias = bq[c];
#pragma unroll
        for (int j = 0; j < 4; ++j)
          Fo[(size_t)(r0 + j) * 2048 + c] = acc[m][n][j] + bias;
      } else {
        if (n0 < 2048) {
          const float bias = bq[c];
#pragma unroll
          for (int j = 0; j < 4; ++j)
            Qo[(size_t)(r0 + j) * 2048 + c] = f2bf(acc[m][n][j] + bias);
        } else if (n0 < 2560) {
          const int ck = c - 2048;
          const float bias = bk[ck];
#pragma unroll
          for (int j = 0; j < 4; ++j)
            Ko[(size_t)(r0 + j) * 512 + ck] = f2bf(acc[m][n][j] + bias);
        } else {
          const int cv = c - 2560;
          const float bias = bv[cv];
          const int b = r0 >> 11, s = r0 & 2047;
          const int kv = cv >> 7, dh = cv & 127;
          uint32_t lo = (uint32_t)f2bf(acc[m][n][0] + bias) | ((uint32_t)f2bf(acc[m][n][1] + bias) << 16);
          uint32_t hi = (uint32_t)f2bf(acc[m][n][2] + bias) | ((uint32_t)f2bf(acc[m][n][3] + bias) << 16);
          *(uint2*)(Vt + (size_t)(((b << 2) + kv) * 128 + dh) * 2048 + s) = make_uint2(lo, hi);
        }
      }
    }
  }
}

// ---------------------------------------------------------------------------
// Causal GQA flash attention, balanced pairs + double-buffered K/V staging.
// Block px handles q-tiles {px, 31-px} (33 iterations each, perfectly balanced).
// One __syncthreads per K-tile; prefetch of tile t+1 issued before compute of t.
// Q is pre-scaled by ATT_SCALE (folded into RoPE).
__global__ __launch_bounds__(256) void attn_kernel(
    const uint16_t* __restrict__ Q, const uint16_t* __restrict__ Kb,
    const uint16_t* __restrict__ Vt, uint16_t* __restrict__ O) {
  const int px  = blockIdx.x;          // pair index 0..15
  const int h   = blockIdx.y;
  const int b   = blockIdx.z;
  const int kvh = h >> 2;
  const int tid  = threadIdx.x;
  const int w    = tid >> 6;
  const int lane = tid & 63;
  const int l15 = lane & 15;
  const int l4  = lane >> 4;

  __shared__ uint16_t Ks[2][64 * 128];
  __shared__ uint16_t Vs[2][128 * 64];
  __shared__ uint16_t Ps[4][16 * 64];
  char* PsB = (char*)(Ps[w]);

  const int krow_off = l4;
  const int kscb = l15 << 4;
  const int vrow_off = lane >> 3;
  const int vscb = (lane & 7) << 4;

  auto stageK = [&](int buf, int t) {
    const int kb = t << 6;
#pragma unroll
    for (int i = 0; i < 4; ++i) {
      const int base_r = 16 * w + 4 * i;
      const int r = base_r + krow_off;
      const int scb = kscb ^ ((r & 7) << 4);
      const char* src = (const char*)Kb + ((size_t)(b * 2048 + kb + r) * 512 + kvh * 128) * 2 + scb;
      async_copy16((char*)(Ks[buf]) + base_r * 256, src);
    }
  };
  auto stageV = [&](int buf, int t) {
    const int kb = t << 6;
#pragma unroll
    for (int i = 0; i < 4; ++i) {
      const int base_r = 32 * w + 8 * i;
      const int r = base_r + vrow_off;
      const int scb = vscb ^ ((r & 7) << 4);
      const char* src = (const char*)Vt + ((size_t)(((b << 2) + kvh) * 128 + r) * 2048 + kb) * 2 + scb;
      async_copy16((char*)(Vs[buf]) + base_r * 128, src);
    }
  };

  for (int half = 0; half < 2; ++half) {
    const int qt = half ? (31 - px) : px;
    const int qbase = qt << 6;

    bfx8 qf[4];
    {
      const size_t qrow = (size_t)(b * 2048 + qbase + (w << 4) + l15);
      const char* qp = (const char*)(Q + qrow * 2048 + h * 128 + l4 * 8);
#pragma unroll
      for (int kk = 0; kk < 4; ++kk) qf[kk] = *(const bfx8*)(qp + kk * 64);
    }

    floatx4 oacc[8] = {};
    float mrun[4], lrun[4];
#pragma unroll
    for (int j = 0; j < 4; ++j) { mrun[j] = -1e30f; lrun[j] = 0.0f; }

    stageK(0, 0);
    stageV(0, 0);
    __syncthreads();

    for (int t = 0; t <= qt; ++t) {
      const int cur = t & 1;
      if (t < qt) { stageK(cur ^ 1, t + 1); stageV(cur ^ 1, t + 1); }
      char* KsB = (char*)(Ks[cur]);
      char* VsB = (char*)(Vs[cur]);
      const int kb = t << 6;

      // S = Q K^T (Q pre-scaled)
      floatx4 sc[4] = {};
      __builtin_amdgcn_s_setprio(1);
#pragma unroll
      for (int kk = 0; kk < 4; ++kk) {
        const int cb = (kk << 6) + (l4 << 4);
#pragma unroll
        for (int n = 0; n < 4; ++n) {
          const int r = (n << 4) + l15;
          bfx8 kf = *(const bfx8*)(KsB + r * 256 + (cb ^ ((r & 7) << 4)));
          sc[n] = __builtin_amdgcn_mfma_f32_16x16x32_bf16(qf[kk], kf, sc[n], 0, 0, 0);
        }
      }
      __builtin_amdgcn_s_setprio(0);

      float p[4][4];
      const bool diag = (t == qt);
#pragma unroll
      for (int n = 0; n < 4; ++n) {
#pragma unroll
        for (int j = 0; j < 4; ++j) {
          float v = sc[n][j];
          if (diag) {
            const int col = kb + (n << 4) + l15;
            const int row = qbase + (w << 4) + (l4 << 2) + j;
            if (col > row) v = -1e30f;
          }
          p[n][j] = v;
        }
      }

      // online softmax: row max via 16-lane shfl reduce; sum kept per-lane partial
#pragma unroll
      for (int j = 0; j < 4; ++j) {
        float pm = fmaxf(fmaxf(p[0][j], p[1][j]), fmaxf(p[2][j], p[3][j]));
#pragma unroll
        for (int off = 8; off > 0; off >>= 1) pm = fmaxf(pm, __shfl_xor(pm, off, 64));
        const float mnew = fmaxf(mrun[j], pm);
        const float sf = __expf(mrun[j] - mnew);
        mrun[j] = mnew;
        float rs = 0.f;
#pragma unroll
        for (int n = 0; n < 4; ++n) {
          p[n][j] = __expf(p[n][j] - mnew);
          rs += p[n][j];
        }
        lrun[j] = lrun[j] * sf + rs;      // per-lane partial; reduced at epilogue
#pragma unroll
        for (int d = 0; d < 8; ++d) oacc[d][j] *= sf;
      }

      // P -> per-wave LDS (wave-private, no barrier)
#pragma unroll
      for (int n = 0; n < 4; ++n) {
        const int cbw = (n << 5) + (l15 << 1);
#pragma unroll
        for (int j = 0; j < 4; ++j) {
          const int r = (l4 << 2) + j;
          *(uint16_t*)(PsB + r * 128 + (cbw ^ ((r & 7) << 4))) = f2bf(p[n][j]);
        }
      }

      // O += P V
      __builtin_amdgcn_s_setprio(1);
#pragma unroll
      for (int kk = 0; kk < 2; ++kk) {
        const int cb = (kk << 6) + (l4 << 4);
        bfx8 pf = *(const bfx8*)(PsB + l15 * 128 + (cb ^ ((l15 & 7) << 4)));
#pragma unroll
        for (int d = 0; d < 8; ++d) {
          const int r = (d << 4) + l15;
          bfx8 vf = *(const bfx8*)(VsB + r * 128 + (cb ^ ((r & 7) << 4)));
          oacc[d] = __builtin_amdgcn_mfma_f32_16x16x32_bf16(pf, vf, oacc[d], 0, 0, 0);
        }
      }
      __builtin_amdgcn_s_setprio(0);

      __syncthreads();
    }

    // epilogue: reduce lrun across 16 lanes, normalize, store bf16
#pragma unroll
    for (int j = 0; j < 4; ++j) {
      float l = lrun[j];
#pragma unroll
      for (int off = 8; off > 0; off >>= 1) l += __shfl_xor(l, off, 64);
      const float inv = 1.0f / l;
      const size_t row = (size_t)(b * 2048 + qbase + (w << 4) + (l4 << 2) + j);
#pragma unroll
      for (int d = 0; d < 8; ++d) {
        const int c = h * 128 + (d << 4) + l15;
        O[row * 2048 + c] = f2bf(oacc[d][j] * inv);
      }
    }
  }
}

// ---------------------------------------------------------------------------
extern "C" void kernel_launch(void* const* d_in, const int* in_sizes, int n_in,
                              void* d_out, int out_size, void* d_ws, size_t ws_size,
                              hipStream_t stream) {
  (void)in_sizes; (void)n_in; (void)out_size; (void)ws_size;
  const float* x         = (const float*)d_in[0];
  const float* rope_freq = (const float*)d_in[1];
  const float* wq_w = (const float*)d_in[3];
  const float* wq_b = (const float*)d_in[4];
  const float* wk_w = (const float*)d_in[5];
  const float* wk_b = (const float*)d_in[6];
  const float* wv_w = (const float*)d_in[7];
  const float* wv_b = (const float*)d_in[8];
  const float* wo_w = (const float*)d_in[9];
  const float* wo_b = (const float*)d_in[10];
  float* out = (float*)d_out;

  char* ws = (char*)d_ws;
  uint16_t* xbf = (uint16_t*)(ws + 0);          // 16 MB : x bf16 (4096,2048)
  uint16_t* wqb = (uint16_t*)(ws + 16777216);   //  8 MB
  uint16_t* wkb = (uint16_t*)(ws + 25165824);   //  2 MB
  uint16_t* wvb = (uint16_t*)(ws + 27262976);   //  2 MB
  uint16_t* wob = (uint16_t*)(ws + 29360128);   //  8 MB
  uint16_t* qbf = (uint16_t*)(ws + 37748736);   // 16 MB : Q (token,2048)
  uint16_t* kbf = (uint16_t*)(ws + 54525952);   //  4 MB : K (token,512)
  uint16_t* vtb = (uint16_t*)(ws + 58720256);   //  4 MB : V^T (b,kv,128,2048)
  uint16_t* att = (uint16_t*)(ws + 62914560);   // 16 MB : attn out (token,2048)

  cvt_kernel<<<8192, 256, 0, stream>>>(x, xbf, 8388608);
  cvt_kernel<<<4096, 256, 0, stream>>>(wq_w, wqb, 4194304);
  cvt_kernel<<<1024, 256, 0, stream>>>(wk_w, wkb, 1048576);
  cvt_kernel<<<1024, 256, 0, stream>>>(wv_w, wvb, 1048576);
  cvt_kernel<<<4096, 256, 0, stream>>>(wo_w, wob, 4194304);

  gemm256<256, 2, 0><<<dim3(16, 12), 512, 0, stream>>>(
      xbf, wqb, wkb, wvb, wq_b, wk_b, wv_b, qbf, kbf, vtb, nullptr);

  rope_kernel<<<16384, 256, 0, stream>>>((uint32_t*)qbf, rope_freq, 10, 4194304, ATT_SCALE);
  rope_kernel<<<4096, 256, 0, stream>>>((uint32_t*)kbf, rope_freq, 8, 1048576, 1.0f);

  attn_kernel<<<dim3(16, 16, 2), 256, 0, stream>>>(qbf, kbf, vtb, att);

  gemm256<128, 1, 1><<<dim3(32, 8), 512, 0, stream>>>(
      att, wob, nullptr, nullptr, wo_b, nullptr, nullptr,
      nullptr, nullptr, nullptr, out);
}

// Round 8
// 335.696 us; speedup vs baseline: 1.3572x; 1.0562x over previous
//
#include <hip/hip_runtime.h>
#include <hip/hip_bf16.h>
#include <stdint.h>

typedef float floatx4 __attribute__((ext_vector_type(4)));
typedef __bf16 bfx8 __attribute__((ext_vector_type(8)));

#define ATT_SCALE 0.08838834764831845f

__device__ __forceinline__ uint16_t f2bf(float f) {
  uint32_t u = __float_as_uint(f);
  return (uint16_t)((u + 0x7fffu + ((u >> 16) & 1u)) >> 16);
}
__device__ __forceinline__ float bf2f(uint32_t bits16) {
  return __uint_as_float(bits16 << 16);
}

typedef __attribute__((address_space(3))) uint32_t lds_u32;
typedef const __attribute__((address_space(1))) uint32_t glob_u32;

// async global->LDS, 16B per lane. LDS dest is wave-uniform base + lane*16.
__device__ __forceinline__ void async_copy16(void* lds, const void* g) {
  uint32_t loff = (uint32_t)(uintptr_t)lds;
  loff = (uint32_t)__builtin_amdgcn_readfirstlane((int)loff);
  lds_u32* lp = reinterpret_cast<lds_u32*>(loff);
  glob_u32* gp = reinterpret_cast<glob_u32*>((uintptr_t)g);
  __builtin_amdgcn_global_load_lds(gp, lp, 16, 0, 0);
}

// ---------------------------------------------------------------------------
// fused fp32 -> bf16 convert for all 5 tensors, 4 elems/thread, one launch.
// regions (blocks): x 8192 | wq 4096 | wk 1024 | wv 1024 | wo 4096 = 18432
__global__ void cvt5_kernel(const float* __restrict__ x,  const float* __restrict__ wq,
                            const float* __restrict__ wk, const float* __restrict__ wv,
                            const float* __restrict__ wo,
                            uint16_t* __restrict__ xb,  uint16_t* __restrict__ wqb,
                            uint16_t* __restrict__ wkb, uint16_t* __restrict__ wvb,
                            uint16_t* __restrict__ wob) {
  const int bid = blockIdx.x;
  const float* src; uint16_t* dst; int base;
  if (bid < 8192)       { src = x;  dst = xb;  base = 0; }
  else if (bid < 12288) { src = wq; dst = wqb; base = 8192; }
  else if (bid < 13312) { src = wk; dst = wkb; base = 12288; }
  else if (bid < 14336) { src = wv; dst = wvb; base = 13312; }
  else                  { src = wo; dst = wob; base = 14336; }
  const int i = (((bid - base) << 8) + threadIdx.x) << 2;
  const float4 v = *(const float4*)(src + i);
  uint32_t lo = (uint32_t)f2bf(v.x) | ((uint32_t)f2bf(v.y) << 16);
  uint32_t hi = (uint32_t)f2bf(v.z) | ((uint32_t)f2bf(v.w) << 16);
  *(uint2*)(dst + i) = make_uint2(lo, hi);
}

// ---------------------------------------------------------------------------
// fused in-place RoPE for Q (pre-scaled by ATT_SCALE) and K, one launch.
// Q: 4194304 pairs (16384 blocks, ncols 2048); K: 1048576 pairs (4096 blocks).
__global__ void rope2_kernel(uint32_t* __restrict__ qb, uint32_t* __restrict__ kb,
                             const float* __restrict__ freq) {
  const int bid = blockIdx.x;
  uint32_t* buf; int idx, shift; float post;
  if (bid < 16384) { buf = qb; idx = (bid << 8) + threadIdx.x; shift = 10; post = ATT_SCALE; }
  else { buf = kb; idx = ((bid - 16384) << 8) + threadIdx.x; shift = 8; post = 1.0f; }
  const int row = idx >> shift;
  const int cp  = idx & ((1 << shift) - 1);
  const int s = row & 2047;
  const int f = cp & 63;
  const float fr = freq[(s << 6) + f];
  float sn, c;
  sincosf(fr, &sn, &c);
  const uint32_t u = buf[idx];
  const float xr = bf2f(u & 0xffffu);
  const float xi = bf2f(u >> 16);
  const float orr = (xr * c - xi * sn) * post;
  const float oi  = (xr * sn + xi * c) * post;
  buf[idx] = (uint32_t)f2bf(orr) | ((uint32_t)f2bf(oi) << 16);
}

// ---------------------------------------------------------------------------
// Deep-pipelined GEMM: C[M][N=...] = A[M x 2048] * W[N x 2048]^T (+bias).
// BK=32, TRIPLE-buffered LDS, one s_barrier + counted vmcnt per K-tile.
// Waves 2(M) x 4(N); per-wave output (BM/2) x 64. BN=256.
// Per K-tile t: read frags from buf[t%3]; stage tile t+2 into buf[(t+2)%3]
// (that buffer's tile t-1 reads completed before the previous barrier);
// lgkmcnt(0) BEFORE the barrier so no wave's reads are in flight when other
// waves (post-barrier, tile t+1) stage into buf[(t+3)%3] == buf[t%3].
// vmcnt(NLW) retires tile t+1's loads; t+2's stay in flight across barriers.
// LDS rows are 64B (32 cols); granule swizzle g^(r&3) both sides (4-way max).
// MODE 0: QKV fused epilogue (Q/K bf16 token-major, V bf16 transposed)
// MODE 1: fp32 out + bias
template <int BM, int MODE>
__global__ __launch_bounds__(512, 2) void gemm3(
    const uint16_t* __restrict__ A,
    const uint16_t* __restrict__ Wq, const uint16_t* __restrict__ Wk,
    const uint16_t* __restrict__ Wv,
    const float* __restrict__ bq, const float* __restrict__ bk,
    const float* __restrict__ bv,
    uint16_t* __restrict__ Qo, uint16_t* __restrict__ Ko,
    uint16_t* __restrict__ Vt, float* __restrict__ Fo) {
  constexpr int NT  = 64;            // K=2048 / BK=32
  constexpr int MR  = BM / 32;       // m-frags per wave (8 or 4)
  constexpr int NLW = BM / 128 + 2;  // stage instrs per tile per wave (4 or 3)

  const int tid  = threadIdx.x;
  const int w    = tid >> 6;
  const int lane = tid & 63;
  const int l15  = lane & 15;
  const int l4   = lane >> 4;
  const int wr   = w >> 2;           // 0..1
  const int wc   = w & 3;            // 0..3
  const int bm = blockIdx.x * BM;
  const int n0 = blockIdx.y * 256;

  const uint16_t* Wp;
  int wrow;
  if constexpr (MODE == 0) {
    if (n0 < 2048)      { Wp = Wq; wrow = n0; }
    else if (n0 < 2560) { Wp = Wk; wrow = n0 - 2048; }
    else                { Wp = Wv; wrow = n0 - 2560; }
  } else {
    Wp = Wq; wrow = n0;
  }

  __shared__ uint16_t As[3][BM * 32];
  __shared__ uint16_t Bs[3][256 * 32];

  floatx4 acc[MR][4] = {};

  const int srow = lane >> 2;        // 0..15 (row within 16-row copy)
  const int sg   = lane & 3;         // source granule selector

  auto stageA = [&](int buf, int t) {
#pragma unroll
    for (int i = 0; i < BM / 128; ++i) {
      const int r0i = w * (BM / 8) + i * 16;
      const int r = r0i + srow;
      const char* src = (const char*)A +
          ((size_t)(bm + r) * 2048 + t * 32) * 2 + ((sg ^ (r & 3)) << 4);
      async_copy16((char*)(As[buf]) + r0i * 64, src);
    }
  };
  auto stageB = [&](int buf, int t) {
#pragma unroll
    for (int i = 0; i < 2; ++i) {
      const int r0i = w * 32 + i * 16;
      const int r = r0i + srow;
      const char* src = (const char*)Wp +
          ((size_t)(wrow + r) * 2048 + t * 32) * 2 + ((sg ^ (r & 3)) << 4);
      async_copy16((char*)(Bs[buf]) + r0i * 64, src);
    }
  };

  // prologue: tiles 0,1 into bufs 0,1; wait for tile 0 only.
  stageA(0, 0); stageB(0, 0);
  stageA(1, 1); stageB(1, 1);
  asm volatile("s_waitcnt vmcnt(%0)" :: "i"(NLW) : "memory");
  __builtin_amdgcn_s_barrier();

  int c0 = 0;
  for (int t = 0; t < NT; ++t) {
    const char* AsB = (const char*)(As[c0]);
    const char* BsB = (const char*)(Bs[c0]);

    bfx8 bf_[4], af_[MR];
#pragma unroll
    for (int n = 0; n < 4; ++n) {
      const int r = wc * 64 + n * 16 + l15;
      bf_[n] = *(const bfx8*)(BsB + r * 64 + ((l4 ^ (r & 3)) << 4));
    }
#pragma unroll
    for (int m = 0; m < MR; ++m) {
      const int r = wr * (BM / 2) + m * 16 + l15;
      af_[m] = *(const bfx8*)(AsB + r * 64 + ((l4 ^ (r & 3)) << 4));
    }

    int c2 = c0 + 2; if (c2 >= 3) c2 -= 3;
    if (t + 2 < NT) { stageA(c2, t + 2); stageB(c2, t + 2); }

    asm volatile("s_waitcnt lgkmcnt(0)" ::: "memory");
    __builtin_amdgcn_sched_barrier(0);
    __builtin_amdgcn_s_setprio(1);
#pragma unroll
    for (int m = 0; m < MR; ++m)
#pragma unroll
      for (int n = 0; n < 4; ++n)
        acc[m][n] = __builtin_amdgcn_mfma_f32_16x16x32_bf16(af_[m], bf_[n], acc[m][n], 0, 0, 0);
    __builtin_amdgcn_s_setprio(0);

    if (t + 2 < NT)      asm volatile("s_waitcnt vmcnt(%0)" :: "i"(NLW) : "memory");
    else if (t + 1 < NT) asm volatile("s_waitcnt vmcnt(0)" ::: "memory");
    if (t + 1 < NT) __builtin_amdgcn_s_barrier();
    if (++c0 == 3) c0 = 0;
  }

  // epilogue: D row = (lane>>4)*4 + reg, col = lane&15
  const int rb = bm + wr * (BM / 2) + (l4 << 2);
  const int cl = wc * 64 + l15;
#pragma unroll
  for (int n = 0; n < 4; ++n) {
    const int c = n0 + cl + (n << 4);
#pragma unroll
    for (int m = 0; m < MR; ++m) {
      const int r0 = rb + (m << 4);
      if constexpr (MODE == 1) {
        const float bias = bq[c];
#pragma unroll
        for (int j = 0; j < 4; ++j)
          Fo[(size_t)(r0 + j) * 2048 + c] = acc[m][n][j] + bias;
      } else {
        if (n0 < 2048) {
          const float bias = bq[c];
#pragma unroll
          for (int j = 0; j < 4; ++j)
            Qo[(size_t)(r0 + j) * 2048 + c] = f2bf(acc[m][n][j] + bias);
        } else if (n0 < 2560) {
          const int ck = c - 2048;
          const float bias = bk[ck];
#pragma unroll
          for (int j = 0; j < 4; ++j)
            Ko[(size_t)(r0 + j) * 512 + ck] = f2bf(acc[m][n][j] + bias);
        } else {
          const int cv = c - 2560;
          const float bias = bv[cv];
          const int b = r0 >> 11, s = r0 & 2047;
          const int kv = cv >> 7, dh = cv & 127;
          uint32_t lo = (uint32_t)f2bf(acc[m][n][0] + bias) | ((uint32_t)f2bf(acc[m][n][1] + bias) << 16);
          uint32_t hi = (uint32_t)f2bf(acc[m][n][2] + bias) | ((uint32_t)f2bf(acc[m][n][3] + bias) << 16);
          *(uint2*)(Vt + (size_t)(((b << 2) + kv) * 128 + dh) * 2048 + s) = make_uint2(lo, hi);
        }
      }
    }
  }
}

// ---------------------------------------------------------------------------
// Causal GQA flash attention, balanced pairs + double-buffered K/V staging.
// Block px handles q-tiles {px, 31-px}; one __syncthreads per K-tile;
// prefetch of tile t+1 issued before compute of t. Q pre-scaled by ATT_SCALE.
__global__ __launch_bounds__(256) void attn_kernel(
    const uint16_t* __restrict__ Q, const uint16_t* __restrict__ Kb,
    const uint16_t* __restrict__ Vt, uint16_t* __restrict__ O) {
  const int px  = blockIdx.x;          // pair index 0..15
  const int h   = blockIdx.y;
  const int b   = blockIdx.z;
  const int kvh = h >> 2;
  const int tid  = threadIdx.x;
  const int w    = tid >> 6;
  const int lane = tid & 63;
  const int l15 = lane & 15;
  const int l4  = lane >> 4;

  __shared__ uint16_t Ks[2][64 * 128];
  __shared__ uint16_t Vs[2][128 * 64];
  __shared__ uint16_t Ps[4][16 * 64];
  char* PsB = (char*)(Ps[w]);

  const int krow_off = l4;
  const int kscb = l15 << 4;
  const int vrow_off = lane >> 3;
  const int vscb = (lane & 7) << 4;

  auto stageK = [&](int buf, int t) {
    const int kb = t << 6;
#pragma unroll
    for (int i = 0; i < 4; ++i) {
      const int base_r = 16 * w + 4 * i;
      const int r = base_r + krow_off;
      const int scb = kscb ^ ((r & 7) << 4);
      const char* src = (const char*)Kb + ((size_t)(b * 2048 + kb + r) * 512 + kvh * 128) * 2 + scb;
      async_copy16((char*)(Ks[buf]) + base_r * 256, src);
    }
  };
  auto stageV = [&](int buf, int t) {
    const int kb = t << 6;
#pragma unroll
    for (int i = 0; i < 4; ++i) {
      const int base_r = 32 * w + 8 * i;
      const int r = base_r + vrow_off;
      const int scb = vscb ^ ((r & 7) << 4);
      const char* src = (const char*)Vt + ((size_t)(((b << 2) + kvh) * 128 + r) * 2048 + kb) * 2 + scb;
      async_copy16((char*)(Vs[buf]) + base_r * 128, src);
    }
  };

  for (int half = 0; half < 2; ++half) {
    const int qt = half ? (31 - px) : px;
    const int qbase = qt << 6;

    bfx8 qf[4];
    {
      const size_t qrow = (size_t)(b * 2048 + qbase + (w << 4) + l15);
      const char* qp = (const char*)(Q + qrow * 2048 + h * 128 + l4 * 8);
#pragma unroll
      for (int kk = 0; kk < 4; ++kk) qf[kk] = *(const bfx8*)(qp + kk * 64);
    }

    floatx4 oacc[8] = {};
    float mrun[4], lrun[4];
#pragma unroll
    for (int j = 0; j < 4; ++j) { mrun[j] = -1e30f; lrun[j] = 0.0f; }

    stageK(0, 0);
    stageV(0, 0);
    __syncthreads();

    for (int t = 0; t <= qt; ++t) {
      const int cur = t & 1;
      if (t < qt) { stageK(cur ^ 1, t + 1); stageV(cur ^ 1, t + 1); }
      char* KsB = (char*)(Ks[cur]);
      char* VsB = (char*)(Vs[cur]);
      const int kb = t << 6;

      // S = Q K^T (Q pre-scaled)
      floatx4 sc[4] = {};
      __builtin_amdgcn_s_setprio(1);
#pragma unroll
      for (int kk = 0; kk < 4; ++kk) {
        const int cb = (kk << 6) + (l4 << 4);
#pragma unroll
        for (int n = 0; n < 4; ++n) {
          const int r = (n << 4) + l15;
          bfx8 kf = *(const bfx8*)(KsB + r * 256 + (cb ^ ((r & 7) << 4)));
          sc[n] = __builtin_amdgcn_mfma_f32_16x16x32_bf16(qf[kk], kf, sc[n], 0, 0, 0);
        }
      }
      __builtin_amdgcn_s_setprio(0);

      float p[4][4];
      const bool diag = (t == qt);
#pragma unroll
      for (int n = 0; n < 4; ++n) {
#pragma unroll
        for (int j = 0; j < 4; ++j) {
          float v = sc[n][j];
          if (diag) {
            const int col = kb + (n << 4) + l15;
            const int row = qbase + (w << 4) + (l4 << 2) + j;
            if (col > row) v = -1e30f;
          }
          p[n][j] = v;
        }
      }

      // online softmax: row max via 16-lane shfl reduce; sum kept per-lane partial
#pragma unroll
      for (int j = 0; j < 4; ++j) {
        float pm = fmaxf(fmaxf(p[0][j], p[1][j]), fmaxf(p[2][j], p[3][j]));
#pragma unroll
        for (int off = 8; off > 0; off >>= 1) pm = fmaxf(pm, __shfl_xor(pm, off, 64));
        const float mnew = fmaxf(mrun[j], pm);
        const float sf = __expf(mrun[j] - mnew);
        mrun[j] = mnew;
        float rs = 0.f;
#pragma unroll
        for (int n = 0; n < 4; ++n) {
          p[n][j] = __expf(p[n][j] - mnew);
          rs += p[n][j];
        }
        lrun[j] = lrun[j] * sf + rs;      // per-lane partial; reduced at epilogue
#pragma unroll
        for (int d = 0; d < 8; ++d) oacc[d][j] *= sf;
      }

      // P -> per-wave LDS (wave-private, no barrier)
#pragma unroll
      for (int n = 0; n < 4; ++n) {
        const int cbw = (n << 5) + (l15 << 1);
#pragma unroll
        for (int j = 0; j < 4; ++j) {
          const int r = (l4 << 2) + j;
          *(uint16_t*)(PsB + r * 128 + (cbw ^ ((r & 7) << 4))) = f2bf(p[n][j]);
        }
      }

      // O += P V
      __builtin_amdgcn_s_setprio(1);
#pragma unroll
      for (int kk = 0; kk < 2; ++kk) {
        const int cb = (kk << 6) + (l4 << 4);
        bfx8 pf = *(const bfx8*)(PsB + l15 * 128 + (cb ^ ((l15 & 7) << 4)));
#pragma unroll
        for (int d = 0; d < 8; ++d) {
          const int r = (d << 4) + l15;
          bfx8 vf = *(const bfx8*)(VsB + r * 128 + (cb ^ ((r & 7) << 4)));
          oacc[d] = __builtin_amdgcn_mfma_f32_16x16x32_bf16(pf, vf, oacc[d], 0, 0, 0);
        }
      }
      __builtin_amdgcn_s_setprio(0);

      __syncthreads();
    }

    // epilogue: reduce lrun across 16 lanes, normalize, store bf16
#pragma unroll
    for (int j = 0; j < 4; ++j) {
      float l = lrun[j];
#pragma unroll
      for (int off = 8; off > 0; off >>= 1) l += __shfl_xor(l, off, 64);
      const float inv = 1.0f / l;
      const size_t row = (size_t)(b * 2048 + qbase + (w << 4) + (l4 << 2) + j);
#pragma unroll
      for (int d = 0; d < 8; ++d) {
        const int c = h * 128 + (d << 4) + l15;
        O[row * 2048 + c] = f2bf(oacc[d][j] * inv);
      }
    }
  }
}

// ---------------------------------------------------------------------------
extern "C" void kernel_launch(void* const* d_in, const int* in_sizes, int n_in,
                              void* d_out, int out_size, void* d_ws, size_t ws_size,
                              hipStream_t stream) {
  (void)in_sizes; (void)n_in; (void)out_size; (void)ws_size;
  const float* x         = (const float*)d_in[0];
  const float* rope_freq = (const float*)d_in[1];
  const float* wq_w = (const float*)d_in[3];
  const float* wq_b = (const float*)d_in[4];
  const float* wk_w = (const float*)d_in[5];
  const float* wk_b = (const float*)d_in[6];
  const float* wv_w = (const float*)d_in[7];
  const float* wv_b = (const float*)d_in[8];
  const float* wo_w = (const float*)d_in[9];
  const float* wo_b = (const float*)d_in[10];
  float* out = (float*)d_out;

  char* ws = (char*)d_ws;
  uint16_t* xbf = (uint16_t*)(ws + 0);          // 16 MB : x bf16 (4096,2048)
  uint16_t* wqb = (uint16_t*)(ws + 16777216);   //  8 MB
  uint16_t* wkb = (uint16_t*)(ws + 25165824);   //  2 MB
  uint16_t* wvb = (uint16_t*)(ws + 27262976);   //  2 MB
  uint16_t* wob = (uint16_t*)(ws + 29360128);   //  8 MB
  uint16_t* qbf = (uint16_t*)(ws + 37748736);   // 16 MB : Q (token,2048)
  uint16_t* kbf = (uint16_t*)(ws + 54525952);   //  4 MB : K (token,512)
  uint16_t* vtb = (uint16_t*)(ws + 58720256);   //  4 MB : V^T (b,kv,128,2048)
  uint16_t* att = (uint16_t*)(ws + 62914560);   // 16 MB : attn out (token,2048)

  cvt5_kernel<<<18432, 256, 0, stream>>>(x, wq_w, wk_w, wv_w, wo_w,
                                         xbf, wqb, wkb, wvb, wob);

  gemm3<256, 0><<<dim3(16, 12), 512, 0, stream>>>(
      xbf, wqb, wkb, wvb, wq_b, wk_b, wv_b, qbf, kbf, vtb, nullptr);

  rope2_kernel<<<20480, 256, 0, stream>>>((uint32_t*)qbf, (uint32_t*)kbf, rope_freq);

  attn_kernel<<<dim3(16, 16, 2), 256, 0, stream>>>(qbf, kbf, vtb, att);

  gemm3<128, 1><<<dim3(32, 8), 512, 0, stream>>>(
      att, wob, nullptr, nullptr, wo_b, nullptr, nullptr,
      nullptr, nullptr, nullptr, out);
}